// Round 7
// baseline (2304.446 us; speedup 1.0000x reference)
//
#include <hip/hip_runtime.h>
#include <hip/hip_bf16.h>

#define D_MODEL 256
#define D_STATE 64
#define MCON    64
#define TLEN    1024
#define BATCH   4
#define NEG_INF -1e9f
#define CSTRIDE 68

// Raw workgroup barrier: LDS-ordered only (no vmcnt(0) drain of global ops).
// __syncthreads() would drain the t+1 prefetch + y-store at every barrier.
#define BAR() asm volatile("s_waitcnt lgkmcnt(0)\n\ts_barrier" ::: "memory")

// ---------------- DPP wave-64 helpers (ctrl as template constants) ---------
template <int CTRL, int RM>
__device__ __forceinline__ float dpp_f(float x) {
    int xi = __float_as_int(x);
    int r  = __builtin_amdgcn_update_dpp(xi, xi, CTRL, RM, 0xf, false);
    return __int_as_float(r);
}
template <int CTRL, int RM>
__device__ __forceinline__ int dpp_i(int x) {
    return __builtin_amdgcn_update_dpp(x, x, CTRL, RM, 0xf, false);
}
__device__ __forceinline__ float bcast_lane(float x, int lane) {
    return __int_as_float(__builtin_amdgcn_readlane(__float_as_int(x), lane));
}
__device__ __forceinline__ float wave_sum(float x) {
    x += dpp_f<0x111, 0xf>(x);   // row_shr:1
    x += dpp_f<0x112, 0xf>(x);   // row_shr:2
    x += dpp_f<0x114, 0xf>(x);   // row_shr:4
    x += dpp_f<0x118, 0xf>(x);   // row_shr:8
    x += dpp_f<0x142, 0xa>(x);   // row_bcast15
    x += dpp_f<0x143, 0xc>(x);   // row_bcast31
    return bcast_lane(x, 63);
}
__device__ __forceinline__ float wave_max(float x) {
    x = fmaxf(x, dpp_f<0x111, 0xf>(x));
    x = fmaxf(x, dpp_f<0x112, 0xf>(x));
    x = fmaxf(x, dpp_f<0x114, 0xf>(x));
    x = fmaxf(x, dpp_f<0x118, 0xf>(x));
    x = fmaxf(x, dpp_f<0x142, 0xa>(x));
    x = fmaxf(x, dpp_f<0x143, 0xc>(x));
    return bcast_lane(x, 63);
}
template <int CTRL, int RM>
__device__ __forceinline__ void maxarg_stage(float& v, int& i) {
    float ov = dpp_f<CTRL, RM>(v);
    int   oi = dpp_i<CTRL, RM>(i);
    const bool better = (ov > v) || (ov == v && oi < i);
    v = better ? ov : v;
    i = better ? oi : i;
}
__device__ __forceinline__ int wave_argmax(float v, int lane) {
    int i = lane;
    maxarg_stage<0x111, 0xf>(v, i);
    maxarg_stage<0x112, 0xf>(v, i);
    maxarg_stage<0x114, 0xf>(v, i);
    maxarg_stage<0x118, 0xf>(v, i);
    maxarg_stage<0x142, 0xa>(v, i);
    maxarg_stage<0x143, 0xc>(v, i);
    return __builtin_amdgcn_readlane(i, 63);
}
// quad-perm sums: xor1 = [1,0,3,2] = 0xB1, xor2 = [2,3,0,1] = 0x4E
template <int CTRL>
__device__ __forceinline__ float dppq(float x) {
    int xi = __float_as_int(x);
    return __int_as_float(__builtin_amdgcn_update_dpp(xi, xi, CTRL, 0xf, 0xf, false));
}

// ---------------------------------------------------------------------------
// Kernel 1: per-token projections (unchanged — passed R2/R3/R5/R6).
// ---------------------------------------------------------------------------
__global__ __launch_bounds__(256) void proj_kernel(
    const float* __restrict__ x,
    const float* __restrict__ Wq, const float* __restrict__ bq,
    const float* __restrict__ Wk, const float* __restrict__ bk,
    const float* __restrict__ Wv, const float* __restrict__ bv,
    float* __restrict__ q_ws, float* __restrict__ k_ws, float* __restrict__ v_ws)
{
    const int token = blockIdx.x;
    const int tid = threadIdx.x;
    __shared__ float sx[D_MODEL];
    sx[tid] = x[token * D_MODEL + tid];
    __syncthreads();

    float acc = 0.f;
    #pragma unroll 8
    for (int i = 0; i < D_MODEL; ++i)
        acc += sx[i] * Wv[i * D_MODEL + tid];
    acc += bv[tid];
    v_ws[token * D_MODEL + tid] = acc;

    if (tid < 128) {
        const int j = tid & 63;
        const float* W  = (tid < 64) ? Wq : Wk;
        const float* bb = (tid < 64) ? bq : bk;
        float a = 0.f;
        #pragma unroll 8
        for (int i = 0; i < D_MODEL; ++i)
            a += sx[i] * W[i * D_STATE + j];
        a += bb[j];
        float s2 = a * a;
        #pragma unroll
        for (int off = 1; off < 64; off <<= 1) s2 += __shfl_xor(s2, off, 64);
        float nrm = fmaxf(sqrtf(s2), 1e-12f);
        float o = a / nrm;
        if (tid < 64) q_ws[token * D_STATE + j] = o;
        else          k_ws[token * D_STATE + j] = o;
    }
}

// ---------------------------------------------------------------------------
// Kernel 2: 4-wave scan, V in registers, raw lgkm-only barriers (3/step).
// Numerics bit-identical to R6 (passed, absmax 9.8e-4).
// ---------------------------------------------------------------------------
__global__ __launch_bounds__(256) void scan_kernel(
    const float* __restrict__ q_ws, const float* __restrict__ k_ws,
    const float* __restrict__ v_ws, float* __restrict__ y_ws,
    const float* __restrict__ ls_p)
{
    const int b   = blockIdx.x;
    const int tid = threadIdx.x;
    const int l   = tid & 63;
    const int wv  = tid >> 6;
    const float scale = fminf(expf(ls_p[0]), 100.f);

    __shared__ __align__(16) float sC[MCON * CSTRIDE];  // 17.4 KB
    __shared__ __align__(16) float sQ[D_STATE];
    __shared__ __align__(16) float sSims[MCON];
    __shared__ __align__(16) float sZ[4 * D_MODEL];     // 4 KB partials
    __shared__ float sRes;

    for (int i = tid; i < MCON * CSTRIDE; i += 256) sC[i] = 0.f;

    float4 Vreg[16];
    #pragma unroll
    for (int j = 0; j < 16; ++j) Vreg[j] = make_float4(0.f, 0.f, 0.f, 0.f);
    float cnt_l = 0.f;   // counts[l], replicated per wave
    int n = 0;           // replicated

    const float* qg = q_ws + b * TLEN * D_STATE;
    const float* kg = k_ws + b * TLEN * D_STATE;
    const float* vg = v_ws + b * TLEN * D_MODEL;
    float*       yg = y_ws + b * TLEN * D_MODEL;

    float  qr = (wv == 0) ? qg[l] : 0.f;
    float  kr = (wv == 3) ? kg[l] : 0.f;
    float4 vr = *(const float4*)&vg[4 * l];

    const int row  = (wv << 4) + (l >> 2);   // sims row this lane covers
    const int part = l & 3;                  // 16-elem part within the row

    __syncthreads();   // init visible (cold path, full barrier OK)

    for (int t = 0; t < TLEN; ++t) {
        if (wv == 0) sQ[l] = qr;
        const float  kk = kr;
        const float4 vt = vr;
        BAR();   // B0: sQ + prev-step C writes visible (no vmcnt drain)

        // prefetch t+1 (not waited on until next step's top)
        const int tn = (t + 1 < TLEN) ? t + 1 : t;
        const float  qn = (wv == 0) ? qg[tn * D_STATE + l] : 0.f;
        const float  kn = (wv == 3) ? kg[tn * D_STATE + l] : 0.f;
        const float4 vn = *(const float4*)&vg[tn * D_MODEL + 4 * l];

        // ---- sims distributed: lane covers (row, part); tree == R5/R6 ----
        float acc = 0.f;
        #pragma unroll
        for (int j = 0; j < 4; ++j) {
            const float4 c4 = *(const float4*)&sC[row * CSTRIDE + part * 16 + 4 * j];
            const float4 q4 = *(const float4*)&sQ[part * 16 + 4 * j];
            acc += c4.x * q4.x; acc += c4.y * q4.y;
            acc += c4.z * q4.z; acc += c4.w * q4.w;
        }
        acc += dppq<0xB1>(acc);   // p0+p1
        acc += dppq<0x4E>(acc);   // + (p2+p3)
        if (part == 0) sSims[row] = acc;
        BAR();   // B1: sims visible

        // ---- softmax + argmax, redundant on all waves (bit-identical) ----
        const float simv = sSims[l];
        const float lg = ((l < n) ? simv : NEG_INF) * scale;
        const float mx = wave_max(lg);
        const float e  = expf(lg - mx);
        const float sm = wave_sum(e);
        const float w  = e / sm;
        const int   sel    = wave_argmax(w, l);
        const float selSim = bcast_lane(simv,  sel);
        const float cnt    = bcast_lane(cnt_l, sel);

        // hoisted C[sel] read (value used only post-B2; hides LDS latency)
        float c_pre = 0.f;
        if (wv == 3) c_pre = sC[sel * CSTRIDE + l];

        // ---- z partial over this wave's 16 rows (pre-update V) ----
        const int wbits = __float_as_int(w);
        const int base  = wv << 4;
        float4 zp = make_float4(0.f, 0.f, 0.f, 0.f);
        #pragma unroll
        for (int j = 0; j < 16; ++j) {
            const float wj = __int_as_float(__builtin_amdgcn_readlane(wbits, base + j));
            zp.x += wj * Vreg[j].x; zp.y += wj * Vreg[j].y;
            zp.z += wj * Vreg[j].z; zp.w += wj * Vreg[j].w;
        }
        *(float4*)&sZ[wv * D_MODEL + 4 * l] = zp;

        // ---- owner wave: select V[sel], residual (pre-update) ----
        const int ws_w = sel >> 4, sidx = sel & 15;
        float4 vs = make_float4(0.f, 0.f, 0.f, 0.f);
        if (wv == ws_w) {
            #pragma unroll
            for (int j = 0; j < 16; ++j) {
                const bool c = (j == sidx);
                vs.x = c ? Vreg[j].x : vs.x;
                vs.y = c ? Vreg[j].y : vs.y;
                vs.z = c ? Vreg[j].z : vs.z;
                vs.w = c ? Vreg[j].w : vs.w;
            }
            float r2 = (vs.x - vt.x) * (vs.x - vt.x)
                     + (vs.y - vt.y) * (vs.y - vt.y)
                     + (vs.z - vt.z) * (vs.z - vt.z)
                     + (vs.w - vt.w) * (vs.w - vt.w);
            r2 = wave_sum(r2);
            if (l == 0) sRes = r2;
        }
        BAR();   // B2: z partials + residual visible

        const float residual = sqrtf(sRes * (1.f / 256.f));
        const bool has       = n > 0;
        const bool refine    = has && (n < MCON) &&
                               (selSim < 0.75f || residual > 1.0f);
        const bool do_add    = ((!has) || refine) && (n < MCON);
        const bool do_update = has && !refine;

        // ---- wave 1: combine z partials, store y ----
        if (wv == 1) {
            const float4 z0 = *(const float4*)&sZ[0 * D_MODEL + 4 * l];
            const float4 z1 = *(const float4*)&sZ[1 * D_MODEL + 4 * l];
            const float4 z2 = *(const float4*)&sZ[2 * D_MODEL + 4 * l];
            const float4 z3 = *(const float4*)&sZ[3 * D_MODEL + 4 * l];
            float4 zout;
            zout.x = has ? ((z0.x + z1.x) + (z2.x + z3.x)) : 0.f;
            zout.y = has ? ((z0.y + z1.y) + (z2.y + z3.y)) : 0.f;
            zout.z = has ? ((z0.z + z1.z) + (z2.z + z3.z)) : 0.f;
            zout.w = has ? ((z0.w + z1.w) + (z2.w + z3.w)) : 0.f;
            *(float4*)&yg[t * D_MODEL + 4 * l] = zout;
        }

        // ---- V updates (register scatter on owner waves) ----
        if (do_update && wv == ws_w) {
            float4 nv;
            nv.x = (vs.x * cnt + vt.x) / (cnt + 1.f);
            nv.y = (vs.y * cnt + vt.y) / (cnt + 1.f);
            nv.z = (vs.z * cnt + vt.z) / (cnt + 1.f);
            nv.w = (vs.w * cnt + vt.w) / (cnt + 1.f);
            #pragma unroll
            for (int j = 0; j < 16; ++j) {
                const bool c = (j == sidx);
                Vreg[j].x = c ? nv.x : Vreg[j].x;
                Vreg[j].y = c ? nv.y : Vreg[j].y;
                Vreg[j].z = c ? nv.z : Vreg[j].z;
                Vreg[j].w = c ? nv.w : Vreg[j].w;
            }
        }
        if (do_add && wv == (n >> 4)) {
            const int aidx = n & 15;
            #pragma unroll
            for (int j = 0; j < 16; ++j) {
                const bool c = (j == aidx);
                Vreg[j].x = c ? vt.x : Vreg[j].x;
                Vreg[j].y = c ? vt.y : Vreg[j].y;
                Vreg[j].z = c ? vt.z : Vreg[j].z;
                Vreg[j].w = c ? vt.w : Vreg[j].w;
            }
        }

        // ---- C update on wave 3 (tree == R5/R6; uses hoisted c_pre) ----
        if (wv == 3) {
            if (do_update) {
                const float tmp = 0.9f * c_pre + 0.1f * kk;
                const float s2  = wave_sum(tmp * tmp);
                sC[sel * CSTRIDE + l] = tmp / fmaxf(sqrtf(s2), 1e-12f);
            }
            if (do_add) sC[n * CSTRIDE + l] = kk;
        }

        // ---- counts / n (replicated, identical on all waves) ----
        if (l == sel && do_update) cnt_l = cnt + 1.f;
        if (l == n   && do_add)    cnt_l = 1.f;
        n += do_add ? 1 : 0;

        qr = qn; kr = kn; vr = vn;
    }
}

// ---------------------------------------------------------------------------
// Kernel 3: out = y @ Wo + bo (unchanged — passed R2/R3/R5/R6).
// ---------------------------------------------------------------------------
__global__ __launch_bounds__(256) void out_kernel(
    const float* __restrict__ y_ws,
    const float* __restrict__ Wo, const float* __restrict__ bo,
    float* __restrict__ out)
{
    const int token = blockIdx.x;
    const int tid = threadIdx.x;
    __shared__ float sy[D_MODEL];
    sy[tid] = y_ws[token * D_MODEL + tid];
    __syncthreads();
    float acc = 0.f;
    #pragma unroll 8
    for (int i = 0; i < D_MODEL; ++i)
        acc += sy[i] * Wo[i * D_MODEL + tid];
    acc += bo[tid];
    out[token * D_MODEL + tid] = acc;
}

// ---------------------------------------------------------------------------
extern "C" void kernel_launch(void* const* d_in, const int* in_sizes, int n_in,
                              void* d_out, int out_size, void* d_ws, size_t ws_size,
                              hipStream_t stream)
{
    const float* x  = (const float*)d_in[0];
    const float* Wq = (const float*)d_in[1];
    const float* bq = (const float*)d_in[2];
    const float* Wk = (const float*)d_in[3];
    const float* bk = (const float*)d_in[4];
    const float* Wv = (const float*)d_in[5];
    const float* bv = (const float*)d_in[6];
    const float* Wo = (const float*)d_in[7];
    const float* bo = (const float*)d_in[8];
    const float* ls = (const float*)d_in[9];
    float* out = (float*)d_out;

    const int NTOK = BATCH * TLEN;                 // 4096
    char* ws = (char*)d_ws;
    float* q_ws = (float*)ws;                                       // 1 MB
    float* k_ws = (float*)(ws + (size_t)NTOK * D_STATE * 4);        // 1 MB
    float* v_ws = (float*)(ws + (size_t)NTOK * D_STATE * 8);        // 4 MB
    float* y_ws = (float*)(ws + (size_t)NTOK * D_STATE * 8
                              + (size_t)NTOK * D_MODEL * 4);        // 4 MB

    proj_kernel<<<NTOK, 256, 0, stream>>>(x, Wq, bq, Wk, bk, Wv, bv,
                                          q_ws, k_ws, v_ws);
    scan_kernel<<<BATCH, 256, 0, stream>>>(q_ws, k_ws, v_ws, y_ws, ls);
    out_kernel<<<NTOK, 256, 0, stream>>>(y_ws, Wo, bo, out);
}

// Round 8
// 1255.509 us; speedup vs baseline: 1.8355x; 1.8355x over previous
//
#include <hip/hip_runtime.h>
#include <hip/hip_bf16.h>

#define D_MODEL 256
#define D_STATE 64
#define MCON    64
#define TLEN    1024
#define BATCH   4
#define NEG_INF -1e9f
#define CSTRIDE 68

// LDS-ordered workgroup barrier (no vmcnt drain; global stores stay in flight)
#define BAR() asm volatile("s_waitcnt lgkmcnt(0)\n\ts_barrier" ::: "memory")

// ---------------- DPP wave-64 helpers ----------------
template <int CTRL, int RM>
__device__ __forceinline__ float dpp_f(float x) {
    int xi = __float_as_int(x);
    int r  = __builtin_amdgcn_update_dpp(xi, xi, CTRL, RM, 0xf, false);
    return __int_as_float(r);
}
template <int CTRL, int RM>
__device__ __forceinline__ int dpp_i(int x) {
    return __builtin_amdgcn_update_dpp(x, x, CTRL, RM, 0xf, false);
}
__device__ __forceinline__ float bcast_lane(float x, int lane) {
    return __int_as_float(__builtin_amdgcn_readlane(__float_as_int(x), lane));
}
__device__ __forceinline__ float wave_sum(float x) {
    x += dpp_f<0x111, 0xf>(x);
    x += dpp_f<0x112, 0xf>(x);
    x += dpp_f<0x114, 0xf>(x);
    x += dpp_f<0x118, 0xf>(x);
    x += dpp_f<0x142, 0xa>(x);
    x += dpp_f<0x143, 0xc>(x);
    return bcast_lane(x, 63);
}
__device__ __forceinline__ float wave_max(float x) {
    x = fmaxf(x, dpp_f<0x111, 0xf>(x));
    x = fmaxf(x, dpp_f<0x112, 0xf>(x));
    x = fmaxf(x, dpp_f<0x114, 0xf>(x));
    x = fmaxf(x, dpp_f<0x118, 0xf>(x));
    x = fmaxf(x, dpp_f<0x142, 0xa>(x));
    x = fmaxf(x, dpp_f<0x143, 0xc>(x));
    return bcast_lane(x, 63);
}
template <int CTRL, int RM>
__device__ __forceinline__ void maxarg_stage(float& v, int& i) {
    float ov = dpp_f<CTRL, RM>(v);
    int   oi = dpp_i<CTRL, RM>(i);
    const bool better = (ov > v) || (ov == v && oi < i);
    v = better ? ov : v;
    i = better ? oi : i;
}
// argmax over scores with first-index tiebreak (R2-validated semantics)
__device__ __forceinline__ int wave_argmax(float v, int lane) {
    int i = lane;
    maxarg_stage<0x111, 0xf>(v, i);
    maxarg_stage<0x112, 0xf>(v, i);
    maxarg_stage<0x114, 0xf>(v, i);
    maxarg_stage<0x118, 0xf>(v, i);
    maxarg_stage<0x142, 0xa>(v, i);
    maxarg_stage<0x143, 0xc>(v, i);
    return __builtin_amdgcn_readlane(i, 63);
}
template <int CTRL>
__device__ __forceinline__ float dppq(float x) {
    int xi = __float_as_int(x);
    return __int_as_float(__builtin_amdgcn_update_dpp(xi, xi, CTRL, 0xf, 0xf, false));
}

// ---------------------------------------------------------------------------
// Kernel 1: per-token projections (unchanged — passed R2..R7).
// ---------------------------------------------------------------------------
__global__ __launch_bounds__(256) void proj_kernel(
    const float* __restrict__ x,
    const float* __restrict__ Wq, const float* __restrict__ bq,
    const float* __restrict__ Wk, const float* __restrict__ bk,
    const float* __restrict__ Wv, const float* __restrict__ bv,
    float* __restrict__ q_ws, float* __restrict__ k_ws, float* __restrict__ v_ws)
{
    const int token = blockIdx.x;
    const int tid = threadIdx.x;
    __shared__ float sx[D_MODEL];
    sx[tid] = x[token * D_MODEL + tid];
    __syncthreads();

    float acc = 0.f;
    #pragma unroll 8
    for (int i = 0; i < D_MODEL; ++i)
        acc += sx[i] * Wv[i * D_MODEL + tid];
    acc += bv[tid];
    v_ws[token * D_MODEL + tid] = acc;

    if (tid < 128) {
        const int j = tid & 63;
        const float* W  = (tid < 64) ? Wq : Wk;
        const float* bb = (tid < 64) ? bq : bk;
        float a = 0.f;
        #pragma unroll 8
        for (int i = 0; i < D_MODEL; ++i)
            a += sx[i] * W[i * D_STATE + j];
        a += bb[j];
        float s2 = a * a;
        #pragma unroll
        for (int off = 1; off < 64; off <<= 1) s2 += __shfl_xor(s2, off, 64);
        float nrm = fmaxf(sqrtf(s2), 1e-12f);
        float o = a / nrm;
        if (tid < 64) q_ws[token * D_STATE + j] = o;
        else          k_ws[token * D_STATE + j] = o;
    }
}

// ---------------------------------------------------------------------------
// Kernel 2: CONTROL scan. Sequential part only: sims -> argmax -> residual ->
// C/V/count updates. No softmax-normalization, no z, no y. Logs sims/n/ver
// and the changed V-row per step for the parallel payload kernel.
// Wave roles: all waves sims; wave1 = control; wave0 = q staging; wave2 = logs.
// ---------------------------------------------------------------------------
__global__ __launch_bounds__(256) void scan_kernel(
    const float* __restrict__ q_ws, const float* __restrict__ k_ws,
    const float* __restrict__ v_ws,
    float* __restrict__ sims_ws, int* __restrict__ n_ws,
    int* __restrict__ ver_ws, float* __restrict__ vlog_ws,
    const float* __restrict__ ls_p)
{
    const int b   = blockIdx.x;
    const int tid = threadIdx.x;
    const int l   = tid & 63;
    const int wv  = tid >> 6;
    const float scale = fminf(expf(ls_p[0]), 100.f);

    __shared__ __align__(16) float sC[MCON * CSTRIDE];   // 17.4 KB
    __shared__ __align__(16) float sV[MCON * D_MODEL];   // 64 KB (control wave only)
    __shared__ __align__(16) float sQ[D_STATE];
    __shared__ __align__(16) float sSims[MCON];
    __shared__ int sN;

    for (int i = tid; i < MCON * CSTRIDE; i += 256) sC[i] = 0.f;
    const float4 zero4 = make_float4(0.f, 0.f, 0.f, 0.f);
    #pragma unroll
    for (int i = 0; i < 16; ++i) ((float4*)sV)[i * 256 + tid] = zero4;
    if (tid == 0) sN = 0;

    const float* qg = q_ws + b * TLEN * D_STATE;
    const float* kg = k_ws + b * TLEN * D_STATE;
    const float* vg = v_ws + b * TLEN * D_MODEL;
    float* vlog_b   = vlog_ws + (size_t)b * (TLEN + 1) * D_MODEL;

    // vlog slot 0 = zeros (targets of never-written version pointers)
    if (wv == 3) *(float4*)&vlog_b[4 * l] = zero4;

    // control-wave state
    float cnt_l = 0.f;   // counts[l] (wave 1)
    int   ver_l = 0;     // version pointer for concept l (wave 1)
    int   n     = 0;     // wave 1 register copy

    // prefetch t = 0
    float  kr = 0.f;
    float4 vr = zero4;
    if (wv == 0) sQ[l] = qg[l];
    if (wv == 1) { kr = kg[l]; vr = *(const float4*)&vg[4 * l]; }

    const int row  = (wv << 4) + (l >> 2);
    const int part = l & 3;

    __syncthreads();   // init + sQ(t=0) visible

    for (int t = 0; t < TLEN; ++t) {
        const int token = b * TLEN + t;
        const float  kk = kr;
        const float4 vt = vr;

        // n for the log wave (pre-update; written by wave1 before prev BAR)
        int n_pre = 0;
        if (wv == 2) n_pre = sN;

        // ---- sims distributed (tree bit-identical to R6/R7) ----
        float acc = 0.f;
        #pragma unroll
        for (int j = 0; j < 4; ++j) {
            const float4 c4 = *(const float4*)&sC[row * CSTRIDE + part * 16 + 4 * j];
            const float4 q4 = *(const float4*)&sQ[part * 16 + 4 * j];
            acc += c4.x * q4.x; acc += c4.y * q4.y;
            acc += c4.z * q4.z; acc += c4.w * q4.w;
        }
        acc += dppq<0xB1>(acc);
        acc += dppq<0x4E>(acc);
        if (part == 0) sSims[row] = acc;

        // prefetch t+1 (off the chain)
        const int tn = (t + 1 < TLEN) ? t + 1 : t;
        float  kn = 0.f;
        float4 vn = zero4;
        float  qn = 0.f;
        if (wv == 0) qn = qg[tn * D_STATE + l];
        if (wv == 1) { kn = kg[tn * D_STATE + l];
                       vn = *(const float4*)&vg[tn * D_MODEL + 4 * l]; }

        BAR();   // B1: sSims visible

        if (wv == 2) {
            sims_ws[(size_t)token * MCON + l] = sSims[l];
            if (l == 0) n_ws[token] = n_pre;
        }
        if (wv == 1) {
            ver_ws[(size_t)token * MCON + l] = ver_l;   // pre-update versions
            const float simv = sSims[l];
            const float lg = ((l < n) ? simv : NEG_INF) * scale;
            const int   sel    = wave_argmax(lg, l);    // R2-validated semantics
            const float selSim = bcast_lane(simv,  sel);
            const float cnt    = bcast_lane(cnt_l, sel);

            const float  c_pre = sC[sel * CSTRIDE + l];
            const float4 vs    = *(const float4*)&sV[sel * D_MODEL + 4 * l];

            float r = (vs.x - vt.x) * (vs.x - vt.x)
                    + (vs.y - vt.y) * (vs.y - vt.y)
                    + (vs.z - vt.z) * (vs.z - vt.z)
                    + (vs.w - vt.w) * (vs.w - vt.w);
            const float residual = sqrtf(wave_sum(r) * (1.f / 256.f));

            const bool has       = n > 0;
            const bool refine    = has && (n < MCON) &&
                                   (selSim < 0.75f || residual > 1.0f);
            const bool do_add    = ((!has) || refine) && (n < MCON);
            const bool do_update = has && !refine;
            // exactly one of do_update/do_add holds every step

            float4 nv;
            nv.x = (vs.x * cnt + vt.x) / (cnt + 1.f);
            nv.y = (vs.y * cnt + vt.y) / (cnt + 1.f);
            nv.z = (vs.z * cnt + vt.z) / (cnt + 1.f);
            nv.w = (vs.w * cnt + vt.w) / (cnt + 1.f);

            const int chg = do_update ? sel : n;
            float4 valV;
            valV.x = do_update ? nv.x : vt.x;
            valV.y = do_update ? nv.y : vt.y;
            valV.z = do_update ? nv.z : vt.z;
            valV.w = do_update ? nv.w : vt.w;
            *(float4*)&sV[chg * D_MODEL + 4 * l] = valV;
            *(float4*)&vlog_b[(size_t)(t + 1) * D_MODEL + 4 * l] = valV;

            const float tmp  = 0.9f * c_pre + 0.1f * kk;
            const float s2   = wave_sum(tmp * tmp);
            const float updc = tmp / fmaxf(sqrtf(s2), 1e-12f);
            sC[chg * CSTRIDE + l] = do_update ? updc : kk;

            if (l == sel && do_update) cnt_l = cnt + 1.f;
            if (l == n   && do_add)    cnt_l = 1.f;
            if (l == chg) ver_l = t + 1;
            n += do_add ? 1 : 0;
            if (l == 0) sN = n;
        }
        if (wv == 0) sQ[l] = qn;   // post-B1: prev readers done

        kr = kn; vr = vn;
        BAR();   // B0 of next step: sC/sV/sN/sQ updates visible
    }
}

// ---------------------------------------------------------------------------
// Kernel 3: PAYLOAD — parallel over all 4096 tokens. Softmax from logged
// sims, gather historical V rows via version log, z = w @ V_t, write y.
// ---------------------------------------------------------------------------
__global__ __launch_bounds__(256) void z_kernel(
    const float* __restrict__ sims_ws, const int* __restrict__ n_ws,
    const int* __restrict__ ver_ws, const float* __restrict__ vlog_ws,
    float* __restrict__ y_ws, const float* __restrict__ ls_p)
{
    const int token = blockIdx.x;
    const int b     = token >> 10;           // TLEN = 1024
    const int tid   = threadIdx.x;
    const int l     = tid & 63;
    const int wv    = tid >> 6;
    const float scale = fminf(expf(ls_p[0]), 100.f);

    __shared__ float sWt[MCON];
    __shared__ int   sVer[MCON];
    __shared__ int   sNtok;

    if (tid == 0) sNtok = n_ws[token];
    if (wv == 1) sVer[l] = ver_ws[(size_t)token * MCON + l];
    if (wv == 0) {
        const float simv = sims_ws[(size_t)token * MCON + l];
        // n via scalar load (uniform)
        const int nt = n_ws[token];
        const float lg = ((l < nt) ? simv : NEG_INF) * scale;
        const float mx = wave_max(lg);
        const float e  = expf(lg - mx);
        const float sm = wave_sum(e);
        sWt[l] = e / sm;                      // nt==0 -> NaN, guarded below
    }
    __syncthreads();

    const int nt = sNtok;
    float z = 0.f;
    if (nt > 0) {
        const float* base = vlog_ws + (size_t)b * (TLEN + 1) * D_MODEL;
        #pragma unroll 8
        for (int m = 0; m < MCON; ++m) {
            const float wm = sWt[m];          // 0 for m >= nt
            z += wm * base[(size_t)sVer[m] * D_MODEL + tid];
        }
    }
    y_ws[(size_t)token * D_MODEL + tid] = z;
}

// ---------------------------------------------------------------------------
// Kernel 4: out = y @ Wo + bo (unchanged — passed R2..R7).
// ---------------------------------------------------------------------------
__global__ __launch_bounds__(256) void out_kernel(
    const float* __restrict__ y_ws,
    const float* __restrict__ Wo, const float* __restrict__ bo,
    float* __restrict__ out)
{
    const int token = blockIdx.x;
    const int tid = threadIdx.x;
    __shared__ float sy[D_MODEL];
    sy[tid] = y_ws[token * D_MODEL + tid];
    __syncthreads();
    float acc = 0.f;
    #pragma unroll 8
    for (int i = 0; i < D_MODEL; ++i)
        acc += sy[i] * Wo[i * D_MODEL + tid];
    acc += bo[tid];
    out[token * D_MODEL + tid] = acc;
}

// ---------------------------------------------------------------------------
extern "C" void kernel_launch(void* const* d_in, const int* in_sizes, int n_in,
                              void* d_out, int out_size, void* d_ws, size_t ws_size,
                              hipStream_t stream)
{
    const float* x  = (const float*)d_in[0];
    const float* Wq = (const float*)d_in[1];
    const float* bq = (const float*)d_in[2];
    const float* Wk = (const float*)d_in[3];
    const float* bk = (const float*)d_in[4];
    const float* Wv = (const float*)d_in[5];
    const float* bv = (const float*)d_in[6];
    const float* Wo = (const float*)d_in[7];
    const float* bo = (const float*)d_in[8];
    const float* ls = (const float*)d_in[9];
    float* out = (float*)d_out;

    const int NTOK = BATCH * TLEN;                 // 4096
    char* ws = (char*)d_ws;
    size_t off = 0;
    float* q_ws    = (float*)(ws + off); off += (size_t)NTOK * D_STATE * 4;   // 1 MB
    float* k_ws    = (float*)(ws + off); off += (size_t)NTOK * D_STATE * 4;   // 1 MB
    float* v_ws    = (float*)(ws + off); off += (size_t)NTOK * D_MODEL * 4;   // 4 MB
    float* y_ws    = (float*)(ws + off); off += (size_t)NTOK * D_MODEL * 4;   // 4 MB
    float* sims_ws = (float*)(ws + off); off += (size_t)NTOK * MCON * 4;      // 1 MB
    int*   ver_ws  = (int*)  (ws + off); off += (size_t)NTOK * MCON * 4;      // 1 MB
    int*   n_ws    = (int*)  (ws + off); off += (size_t)NTOK * 4;             // 16 KB
    float* vlog_ws = (float*)(ws + off);                                      // 4.1 MB

    proj_kernel<<<NTOK, 256, 0, stream>>>(x, Wq, bq, Wk, bk, Wv, bv,
                                          q_ws, k_ws, v_ws);
    scan_kernel<<<BATCH, 256, 0, stream>>>(q_ws, k_ws, v_ws,
                                           sims_ws, n_ws, ver_ws, vlog_ws, ls);
    z_kernel<<<NTOK, 256, 0, stream>>>(sims_ws, n_ws, ver_ws, vlog_ws,
                                       y_ws, ls);
    out_kernel<<<NTOK, 256, 0, stream>>>(y_ws, Wo, bo, out);
}